// Round 6
// baseline (262.219 us; speedup 1.0000x reference)
//
#include <hip/hip_runtime.h>
#include <hip/hip_bf16.h>
#include <float.h>
#include <math.h>

#define CDIM 128

typedef __attribute__((ext_vector_type(8))) short short8v;   // 8 bf16 = 1 MFMA A/B frag
typedef __attribute__((ext_vector_type(4))) float f32x4;     // MFMA C/D frag

__device__ __forceinline__ short bf16b(float f) {
    __hip_bfloat16 h = __float2bfloat16(f);
    return __builtin_bit_cast(short, h);
}

// fast tanh via hardware exp: tanh(y) = 1 - 2/(exp(2y)+1)
__device__ __forceinline__ float tanh_fast(float y) {
    float e = __expf(2.0f * y);
    return 1.0f - 2.0f / (e + 1.0f);
}

__device__ __forceinline__ int lower_bound_i(const int* __restrict__ b, int n, int v) {
    int lo = 0, hi = n;
    while (lo < hi) { int mid = (lo + hi) >> 1; if (b[mid] < v) lo = mid + 1; else hi = mid; }
    return lo;
}

__global__ void seg_bounds_kernel(const int* __restrict__ batch, int N, int G,
                                  int* __restrict__ seg) {
    int g = blockIdx.x * blockDim.x + threadIdx.x;
    if (g < G) seg[g] = lower_bound_i(batch, N, g);
    if (g == 0) seg[G] = N;
}

// Pre-pack proj_w into bf16 MFMA B-fragments.
// Frag f = ct*4+ks, lane l: col c = ct*16+(l&15), k = ks*32+(l>>4)*8+j  (j=0..7)
__global__ void wconv_kernel(const float* __restrict__ proj_w, short* __restrict__ wfrag) {
    int tid = blockIdx.x * 256 + threadIdx.x;       // 0..2047
    int f = tid >> 6, l = tid & 63;
    int c  = ((f >> 2) << 4) | (l & 15);
    int k0 = ((f & 3) << 5) | ((l >> 4) << 3);
    short8v v;
    #pragma unroll
    for (int j = 0; j < 8; ++j) v[j] = bf16b(proj_w[c * CDIM + k0 + j]);
    ((short8v*)wfrag)[tid] = v;
}

// ONE WAVE PER GRAPH. 256-thread blocks = 4 independent waves (graphs).
// Zero in-loop barriers: W lives in read-only LDS (one startup barrier);
// x chunks (16 rows) load straight to registers (fp32 kept for exact pooling,
// bf16 A-frags built in-register); softmax + pooling are shuffle/register-only.
// 4096 independent waves all resident -> TLP hides load latency.
__launch_bounds__(256, 4)
__global__ void pool_kernel(const float* __restrict__ x,
                            const short* __restrict__ wfrag,
                            const float* __restrict__ proj_b,
                            const float* __restrict__ score_w,
                            const float* __restrict__ score_b,
                            const int* __restrict__ seg,
                            float* __restrict__ out,
                            int N, int G) {
    __shared__ short8v Wl[2048];              // 32KB: frag f=ct*4+ks at [f*64+lane]
    __shared__ float2  pbsw[128];             // {proj_b[c], score_w[c]}

    const int t = threadIdx.x;
    {   // stage W frags + bias/score vectors (coalesced, once)
        const short8v* wfg = (const short8v*)wfrag;
        #pragma unroll
        for (int i = 0; i < 8; ++i) Wl[t + (i << 8)] = wfg[t + (i << 8)];
        if (t < 128) pbsw[t] = make_float2(proj_b[t], score_w[t]);
    }
    __syncthreads();                          // the ONLY block-wide barrier

    const int lane = t & 63;
    const int g = (blockIdx.x << 2) | (t >> 6);
    if (g >= G) return;
    float* og = out + (size_t)g * CDIM;

    const int start = seg[g];
    const int cnt = seg[g + 1] - start;
    if (cnt <= 0) {                           // empty graph pools to zeros
        if (lane < 32) ((float4*)og)[lane] = make_float4(0.f, 0.f, 0.f, 0.f);
        return;
    }

    const int rl = lane & 15;                 // row-in-chunk (load/pool side)
    const int cg = lane >> 4;                 // k-quarter / row-group (0..3)
    const float sb = score_b[0];

    float m_run = -FLT_MAX, l_run = 0.0f;
    float4 pa[8];
    #pragma unroll
    for (int i = 0; i < 8; ++i) pa[i] = make_float4(0.f, 0.f, 0.f, 0.f);

    for (int cb = 0; cb < cnt; cb += 16) {
        const int rem = cnt - cb;             // >= 1

        // ---- load 16 rows x 128 ch: lane -> row rl, float4s {ks*8 + half} at base cg*2 ----
        const int row = start + cb + min(rl, rem - 1);        // clamp tail (masked later)
        const float4* xp = (const float4*)(x + (size_t)row * CDIM + (cg << 3));
        float4 xr[8];
        #pragma unroll
        for (int ks = 0; ks < 4; ++ks) {
            xr[ks * 2]     = xp[ks * 8];
            xr[ks * 2 + 1] = xp[ks * 8 + 1];
        }

        // ---- bf16 A-frags, in-register (row=rl, k = ks*32 + cg*8 + j) ----
        short8v af[4];
        #pragma unroll
        for (int ks = 0; ks < 4; ++ks) {
            float4 a = xr[ks * 2], b = xr[ks * 2 + 1];
            af[ks][0] = bf16b(a.x); af[ks][1] = bf16b(a.y);
            af[ks][2] = bf16b(a.z); af[ks][3] = bf16b(a.w);
            af[ks][4] = bf16b(b.x); af[ks][5] = bf16b(b.y);
            af[ks][6] = bf16b(b.z); af[ks][7] = bf16b(b.w);
        }

        // ---- scores: 8 col-tiles x 4 k-steps MFMA; tanh/score partial per ct ----
        float scp[4] = {0.f, 0.f, 0.f, 0.f};
        #pragma unroll
        for (int ct = 0; ct < 8; ++ct) {
            f32x4 acc = (f32x4){0.f, 0.f, 0.f, 0.f};
            #pragma unroll
            for (int ks = 0; ks < 4; ++ks)
                acc = __builtin_amdgcn_mfma_f32_16x16x32_bf16(af[ks], Wl[(((ct << 2) | ks) << 6) | lane], acc, 0, 0, 0);
            const float2 pb = pbsw[(ct << 4) | rl];
            #pragma unroll
            for (int r = 0; r < 4; ++r)
                scp[r] += pb.y * tanh_fast(acc[r] + pb.x);    // C/D: col=rl, row=cg*4+r
        }

        // ---- reduce over 16 col-lanes -> row scores (replicated over rl) ----
        float sv[4]; float mx = -FLT_MAX;
        #pragma unroll
        for (int r = 0; r < 4; ++r) {
            float v = scp[r];
            v += __shfl_xor(v, 1); v += __shfl_xor(v, 2);
            v += __shfl_xor(v, 4); v += __shfl_xor(v, 8);
            sv[r] = ((cg << 2) + r < rem) ? (v + sb) : -FLT_MAX;
            mx = fmaxf(mx, sv[r]);
        }
        mx = fmaxf(mx, __shfl_xor(mx, 16));
        mx = fmaxf(mx, __shfl_xor(mx, 32));   // chunk max, all lanes

        // ---- online softmax (all-lane redundant, shuffle-only) ----
        const float m_new = fmaxf(m_run, mx);
        float e_[4]; float ssum = 0.f;
        #pragma unroll
        for (int r = 0; r < 4; ++r) {
            e_[r] = ((cg << 2) + r < rem) ? __expf(sv[r] - m_new) : 0.f;
            ssum += e_[r];
        }
        ssum += __shfl_xor(ssum, 16);
        ssum += __shfl_xor(ssum, 32);         // chunk sum (each row once)
        if (mx > m_run) {                     // rescale only when max grew (uniform)
            const float sc = __expf(m_run - m_new);
            l_run *= sc;
            #pragma unroll
            for (int i = 0; i < 8; ++i) {
                pa[i].x *= sc; pa[i].y *= sc; pa[i].z *= sc; pa[i].w *= sc;
            }
        }
        m_run = m_new;
        l_run += ssum;

        // ---- redistribute e to load-side rows: row rl lives in group rl>>2, slot rl&3 ----
        const int src = (rl >> 2) << 4;
        const float er0 = __shfl(e_[0], src), er1 = __shfl(e_[1], src);
        const float er2 = __shfl(e_[2], src), er3 = __shfl(e_[3], src);
        const int rr = rl & 3;
        const float em = rr == 0 ? er0 : rr == 1 ? er1 : rr == 2 ? er2 : er3;  // 0 for pad rows

        // ---- pooling accumulate (pure registers) ----
        #pragma unroll
        for (int i = 0; i < 8; ++i) {
            pa[i].x += em * xr[i].x; pa[i].y += em * xr[i].y;
            pa[i].z += em * xr[i].z; pa[i].w += em * xr[i].w;
        }
    }

    // ---- cross-row reduce (over rl) + normalize + store ----
    #pragma unroll
    for (int m = 1; m <= 8; m <<= 1) {
        #pragma unroll
        for (int i = 0; i < 8; ++i) {
            pa[i].x += __shfl_xor(pa[i].x, m); pa[i].y += __shfl_xor(pa[i].y, m);
            pa[i].z += __shfl_xor(pa[i].z, m); pa[i].w += __shfl_xor(pa[i].w, m);
        }
    }
    const float inv = 1.0f / fmaxf(l_run, 1e-30f);
    if (rl == 0) {
        float4* o4 = (float4*)og;
        #pragma unroll
        for (int ks = 0; ks < 4; ++ks) {
            #pragma unroll
            for (int half = 0; half < 2; ++half) {
                float4 v = pa[ks * 2 + half];
                v.x *= inv; v.y *= inv; v.z *= inv; v.w *= inv;
                o4[ks * 8 + half + (cg << 1)] = v;
            }
        }
    }
}

extern "C" void kernel_launch(void* const* d_in, const int* in_sizes, int n_in,
                              void* d_out, int out_size, void* d_ws, size_t ws_size,
                              hipStream_t stream) {
    const float* x       = (const float*)d_in[0];
    const float* proj_w  = (const float*)d_in[1];
    const float* proj_b  = (const float*)d_in[2];
    const float* score_w = (const float*)d_in[3];
    const float* score_b = (const float*)d_in[4];
    const int*   batch   = (const int*)d_in[5];

    const int N = in_sizes[0] / CDIM;
    const int G = out_size / CDIM;

    int*   seg   = (int*)d_ws;
    short* wfrag = (short*)((char*)d_ws + (((size_t)(G + 1) * 4 + 255) & ~(size_t)255));

    seg_bounds_kernel<<<(G + 255) / 256, 256, 0, stream>>>(batch, N, G, seg);
    wconv_kernel<<<8, 256, 0, stream>>>(proj_w, wfrag);
    pool_kernel<<<(G + 3) / 4, 256, 0, stream>>>(x, wfrag, proj_b, score_w, score_b,
                                                 seg, (float*)d_out, N, G);
}

// Round 7
// 248.686 us; speedup vs baseline: 1.0544x; 1.0544x over previous
//
#include <hip/hip_runtime.h>
#include <hip/hip_bf16.h>
#include <float.h>
#include <math.h>

#define CDIM 128

typedef __attribute__((ext_vector_type(8))) short short8v;   // 8 bf16 = 1 MFMA A/B frag
typedef __attribute__((ext_vector_type(4))) float f32x4;     // MFMA C/D frag

__device__ __forceinline__ short bf16b(float f) {
    __hip_bfloat16 h = __float2bfloat16(f);
    return __builtin_bit_cast(short, h);
}

// fast tanh via hardware exp: tanh(y) = 1 - 2/(exp(2y)+1)
__device__ __forceinline__ float tanh_fast(float y) {
    float e = __expf(2.0f * y);
    return 1.0f - 2.0f / (e + 1.0f);
}

__device__ __forceinline__ int lower_bound_i(const int* __restrict__ b, int n, int v) {
    int lo = 0, hi = n;
    while (lo < hi) { int mid = (lo + hi) >> 1; if (b[mid] < v) lo = mid + 1; else hi = mid; }
    return lo;
}

__global__ void seg_bounds_kernel(const int* __restrict__ batch, int N, int G,
                                  int* __restrict__ seg) {
    int g = blockIdx.x * blockDim.x + threadIdx.x;
    if (g < G) seg[g] = lower_bound_i(batch, N, g);
    if (g == 0) seg[G] = N;
}

// Pre-pack proj_w into bf16 MFMA B-fragments.
// Frag f = ct*4+ks, lane l: col c = ct*16+(l&15), k = ks*32+(l>>4)*8+j  (j=0..7)
__global__ void wconv_kernel(const float* __restrict__ proj_w, short* __restrict__ wfrag) {
    int tid = blockIdx.x * 256 + threadIdx.x;       // 0..2047
    int f = tid >> 6, l = tid & 63;
    int c  = ((f >> 2) << 4) | (l & 15);
    int k0 = ((f & 3) << 5) | ((l >> 4) << 3);
    short8v v;
    #pragma unroll
    for (int j = 0; j < 8; ++j) v[j] = bf16b(proj_w[c * CDIM + k0 + j]);
    ((short8v*)wfrag)[tid] = v;
}

// swizzled f4-slot within a row: 32B-granule XOR keeps 64B-line coalescing on
// the global side and spreads LDS banks across rows (row stride 512B ≡ 0 mod 128B).
__device__ __forceinline__ int swz_slot(int row, int c4) {
    return (row << 5) | ((((c4 >> 1) ^ (row & 7)) << 1) | (c4 & 1));
}

// One block (4 waves) per graph, R4 skeleton + T14 pipeline:
//  - fp32 x double-buffered in LDS (2x32KB); chunk k+1 loads ISSUE right after
//    the top barrier (hidden under compute), ds_write happens at body end.
//  - wave w owns col-tiles {2w,2w+1} (wf in 32 VGPR); A-frags built per wave
//    from the fp32 tile (redundant cvt, VALU has headroom).
//  - all-wave shuffle softmax (lane = row): no wave0 serialization, 2 barriers/chunk.
//  - (256,2): 256-VGPR cap -> zero spill; occupancy LDS-bound at 2 blocks/CU.
__launch_bounds__(256, 2)
__global__ void pool_kernel(const float* __restrict__ x,
                            const short* __restrict__ wfrag,
                            const float* __restrict__ proj_b,
                            const float* __restrict__ score_w,
                            const float* __restrict__ score_b,
                            const int* __restrict__ seg,
                            float* __restrict__ out,
                            int N) {
    __shared__ float4 Xf[2][64 * 32];         // 64KB fp32 x, swizzled slots
    __shared__ float  ps[64 * 4];             // score partials [row][wave]

    const int g = blockIdx.x;
    const int t = threadIdx.x;
    const int lane = t & 63;
    const int w = t >> 6;                     // wave id: owns col-tiles 2w, 2w+1
    const int start = seg[g];
    const int cnt = seg[g + 1] - start;
    float4* og4 = (float4*)(out + (size_t)g * CDIM);

    if (cnt <= 0) {                           // empty graph pools to zeros
        if (t < 32) og4[t] = make_float4(0.f, 0.f, 0.f, 0.f);
        return;
    }

    const float4* __restrict__ x4 = (const float4*)x;
    const int c4 = t & 31;                    // stage/pool f4 column
    const int rp = t >> 5;                    // stage/pool row phase (0..7)
    const int rl = lane & 15, kq = lane >> 4; // MFMA A side

    // ---- prologue: issue chunk 0 loads first (deepest latency) ----
    float4 xn[8];
    {
        const int rem0 = cnt;
        #pragma unroll
        for (int i = 0; i < 8; ++i) {
            int row = (i << 3) | rp;
            size_t gr = (size_t)(start + min(row, rem0 - 1));
            xn[i] = x4[gr * 32 + c4];
        }
    }

    // W fragments for this wave's 2 col-tiles (32 VGPR) + bias/score slices
    short8v wf[2][4];
    {
        const short8v* wfg = (const short8v*)wfrag;
        #pragma unroll
        for (int j = 0; j < 2; ++j)
            #pragma unroll
            for (int ks = 0; ks < 4; ++ks)
                wf[j][ks] = wfg[((((w << 1) | j) << 2 | ks) << 6) | lane];
    }
    float swl[2], pbl[2];
    #pragma unroll
    for (int j = 0; j < 2; ++j) {
        swl[j] = score_w[(((w << 1) | j) << 4) + rl];
        pbl[j] = proj_b[(((w << 1) | j) << 4) + rl];
    }
    const float sb = score_b[0];

    // write chunk 0 into buffer 0 (compiler waits the loads here)
    #pragma unroll
    for (int i = 0; i < 8; ++i)
        Xf[0][swz_slot((i << 3) | rp, c4)] = xn[i];
    int buf = 0;

    float m_run = -FLT_MAX, l_run = 0.0f;
    float4 pa = make_float4(0.f, 0.f, 0.f, 0.f);

    for (int cb = 0; cb < cnt; cb += 64) {
        const int rem = cnt - cb;
        __syncthreads();                      // top: Xf[buf] ready, Xf[buf^1] free

        // ---- issue chunk k+1 loads EARLY (latency hidden under this body) ----
        const bool pf = (cb + 64 < cnt);
        if (pf) {
            const int rem2 = cnt - cb - 64;
            #pragma unroll
            for (int i = 0; i < 8; ++i) {
                int row = (i << 3) | rp;
                size_t gr = (size_t)(start + cb + 64 + min(row, rem2 - 1));
                xn[i] = x4[gr * 32 + c4];
            }
        }

        // ---- MFMA: 4 row-tiles x this wave's 2 col-tiles; A from fp32 LDS ----
        const float4* Xc = Xf[buf];
        #pragma unroll
        for (int rt = 0; rt < 4; ++rt) {
            const int arow = (rt << 4) | rl;
            short8v af[4];
            #pragma unroll
            for (int ks = 0; ks < 4; ++ks) {
                int q = (arow << 5) | ((((ks << 2) | kq) ^ (arow & 7)) << 1);
                float4 q0 = Xc[q], q1 = Xc[q + 1];
                af[ks][0] = bf16b(q0.x); af[ks][1] = bf16b(q0.y);
                af[ks][2] = bf16b(q0.z); af[ks][3] = bf16b(q0.w);
                af[ks][4] = bf16b(q1.x); af[ks][5] = bf16b(q1.y);
                af[ks][6] = bf16b(q1.z); af[ks][7] = bf16b(q1.w);
            }
            f32x4 a0 = (f32x4){0.f, 0.f, 0.f, 0.f};
            f32x4 a1 = (f32x4){0.f, 0.f, 0.f, 0.f};
            #pragma unroll
            for (int ks = 0; ks < 4; ++ks) {
                a0 = __builtin_amdgcn_mfma_f32_16x16x32_bf16(af[ks], wf[0][ks], a0, 0, 0, 0);
                a1 = __builtin_amdgcn_mfma_f32_16x16x32_bf16(af[ks], wf[1][ks], a1, 0, 0, 0);
            }
            #pragma unroll
            for (int r = 0; r < 4; ++r) {     // C/D: channel=rl, node row = kq*4+r
                float s = swl[0] * tanh_fast(a0[r] + pbl[0])
                        + swl[1] * tanh_fast(a1[r] + pbl[1]);
                s += __shfl_xor(s, 1); s += __shfl_xor(s, 2);
                s += __shfl_xor(s, 4); s += __shfl_xor(s, 8);
                if (rl == 0) ps[(((rt << 4) | (kq << 2) | r) << 2) | w] = s;
            }
        }
        __syncthreads();                      // ps ready

        // ---- all-wave softmax: lane L owns row L (redundant across waves) ----
        float4 pp = *(const float4*)&ps[lane << 2];
        float sv = (lane < rem) ? (pp.x + pp.y + pp.z + pp.w + sb) : -FLT_MAX;
        float mx = sv;
        #pragma unroll
        for (int m = 1; m < 64; m <<= 1) mx = fmaxf(mx, __shfl_xor(mx, m));
        const float m_new = fmaxf(m_run, mx);
        float ev = (lane < rem) ? __expf(sv - m_new) : 0.f;
        float ssum = ev;
        #pragma unroll
        for (int m = 1; m < 64; m <<= 1) ssum += __shfl_xor(ssum, m);
        const float sc = __expf(m_run - m_new);       // first chunk: exp(-inf)=0
        m_run = m_new;
        l_run = l_run * sc + ssum;
        pa.x *= sc; pa.y *= sc; pa.z *= sc; pa.w *= sc;

        // ---- pooling accumulate from fp32 LDS ----
        #pragma unroll
        for (int i = 0; i < 8; ++i) {
            int row = (i << 3) | rp;
            float em = __shfl(ev, row);               // 0 for pad rows
            float4 xv = Xc[swz_slot(row, c4)];
            pa.x += em * xv.x; pa.y += em * xv.y;
            pa.z += em * xv.z; pa.w += em * xv.w;
        }

        // ---- write-late: chunk k+1 into the spare buffer ----
        if (pf) {
            float4* Xn = Xf[buf ^ 1];
            #pragma unroll
            for (int i = 0; i < 8; ++i)
                Xn[swz_slot((i << 3) | rp, c4)] = xn[i];
        }
        buf ^= 1;
    }

    // ---- cross-phase reduce (alias red onto Xf) + normalize + store ----
    __syncthreads();
    float4* red = Xf[0];
    red[(rp << 5) | c4] = pa;
    __syncthreads();
    if (t < 32) {
        float4 v = make_float4(0.f, 0.f, 0.f, 0.f);
        #pragma unroll
        for (int j = 0; j < 8; ++j) {
            float4 r = red[(j << 5) | t];
            v.x += r.x; v.y += r.y; v.z += r.z; v.w += r.w;
        }
        const float inv = 1.0f / fmaxf(l_run, 1e-30f);
        v.x *= inv; v.y *= inv; v.z *= inv; v.w *= inv;
        og4[t] = v;
    }
}

extern "C" void kernel_launch(void* const* d_in, const int* in_sizes, int n_in,
                              void* d_out, int out_size, void* d_ws, size_t ws_size,
                              hipStream_t stream) {
    const float* x       = (const float*)d_in[0];
    const float* proj_w  = (const float*)d_in[1];
    const float* proj_b  = (const float*)d_in[2];
    const float* score_w = (const float*)d_in[3];
    const float* score_b = (const float*)d_in[4];
    const int*   batch   = (const int*)d_in[5];

    const int N = in_sizes[0] / CDIM;
    const int G = out_size / CDIM;

    int*   seg   = (int*)d_ws;
    short* wfrag = (short*)((char*)d_ws + (((size_t)(G + 1) * 4 + 255) & ~(size_t)255));

    seg_bounds_kernel<<<(G + 255) / 256, 256, 0, stream>>>(batch, N, G, seg);
    wconv_kernel<<<8, 256, 0, stream>>>(proj_w, wfrag);
    pool_kernel<<<G, 256, 0, stream>>>(x, wfrag, proj_b, score_w, score_b,
                                       seg, (float*)d_out, N);
}

// Round 8
// 100.497 us; speedup vs baseline: 2.6092x; 2.4746x over previous
//
#include <hip/hip_runtime.h>
#include <hip/hip_bf16.h>
#include <float.h>
#include <math.h>

#define CDIM 128

typedef __attribute__((ext_vector_type(8))) short short8v;   // 8 bf16 = 1 MFMA A/B frag
typedef __attribute__((ext_vector_type(4))) short short4v;   // 4 bf16 (8B LDS store)
typedef __attribute__((ext_vector_type(4))) float f32x4;     // MFMA C/D frag

__device__ __forceinline__ short bf16b(float f) {
    __hip_bfloat16 h = __float2bfloat16(f);
    return __builtin_bit_cast(short, h);
}

// fast tanh via hardware exp: tanh(y) = 1 - 2/(exp(2y)+1)
__device__ __forceinline__ float tanh_fast(float y) {
    float e = __expf(2.0f * y);
    return 1.0f - 2.0f / (e + 1.0f);
}

__device__ __forceinline__ int lower_bound_i(const int* __restrict__ b, int n, int v) {
    int lo = 0, hi = n;
    while (lo < hi) { int mid = (lo + hi) >> 1; if (b[mid] < v) lo = mid + 1; else hi = mid; }
    return lo;
}

__global__ void seg_bounds_kernel(const int* __restrict__ batch, int N, int G,
                                  int* __restrict__ seg) {
    int g = blockIdx.x * blockDim.x + threadIdx.x;
    if (g < G) seg[g] = lower_bound_i(batch, N, g);
    if (g == 0) seg[G] = N;
}

// Pre-pack proj_w into bf16 MFMA B-fragments.
// Frag f = ct*4+ks, lane l: col c = ct*16+(l&15), k = ks*32+(l>>4)*8+j  (j=0..7)
__global__ void wconv_kernel(const float* __restrict__ proj_w, short* __restrict__ wfrag) {
    int tid = blockIdx.x * 256 + threadIdx.x;       // 0..2047
    int f = tid >> 6, l = tid & 63;
    int c  = ((f >> 2) << 4) | (l & 15);
    int k0 = ((f & 3) << 5) | ((l >> 4) << 3);
    short8v v;
    #pragma unroll
    for (int j = 0; j < 8; ++j) v[j] = bf16b(proj_w[c * CDIM + k0 + j]);
    ((short8v*)wfrag)[tid] = v;
}

// One block (4 waves) per graph — R4 skeleton, 2 barriers/chunk:
//  - stage: global -> fp32 regs (kept for exact pooling) + bf16 swizzled LDS
//    (converted once; 16B-granule XOR = conflict-free A-frag ds_read_b128).
//  - wave w owns col-tiles {2w,2w+1} (wf = 32 VGPR); MFMA per row-tile.
//  - ALL-WAVE shuffle softmax from ps (lane = row, redundant across waves):
//    no wave0 serialization, no cs/bc broadcast, one barrier removed.
//  - pooling: pure registers + __shfl of e. Final reduce aliases onto XsB.
__launch_bounds__(256, 4)
__global__ void pool_kernel(const float* __restrict__ x,
                            const short* __restrict__ wfrag,
                            const float* __restrict__ proj_b,
                            const float* __restrict__ score_w,
                            const float* __restrict__ score_b,
                            const int* __restrict__ seg,
                            float* __restrict__ out,
                            int N) {
    // LDS: 16KB XsB + 1KB ps = 17KB
    __shared__ __align__(16) short XsB[64 * 128]; // bf16: row*128 + (k ^ ((row&7)<<3))
    __shared__ float ps[64 * 4];                  // score partials [row][wave]

    const int g = blockIdx.x;
    const int t = threadIdx.x;
    const int lane = t & 63;
    const int w = t >> 6;                     // wave id: owns col-tiles 2w, 2w+1
    const int start = seg[g];
    const int cnt = seg[g + 1] - start;
    float4* og4 = (float4*)(out + (size_t)g * CDIM);

    if (cnt <= 0) {                           // empty graph pools to zeros
        if (t < 32) og4[t] = make_float4(0.f, 0.f, 0.f, 0.f);
        return;
    }

    // W fragments for this wave's 2 column-tiles: 8 frags = 32 VGPR
    short8v wf[2][4];
    {
        const short8v* wfg = (const short8v*)wfrag;
        #pragma unroll
        for (int j = 0; j < 2; ++j)
            #pragma unroll
            for (int ks = 0; ks < 4; ++ks)
                wf[j][ks] = wfg[((((w << 1) | j) << 2 | ks) << 6) | lane];
    }
    const int al = lane & 15, ah = lane >> 4;
    float swl[2], pbl[2];
    #pragma unroll
    for (int j = 0; j < 2; ++j) {
        swl[j] = score_w[(((w << 1) | j) << 4) + al];
        pbl[j] = proj_b[(((w << 1) | j) << 4) + al];
    }
    const float sb = score_b[0];

    const float4* __restrict__ x4 = (const float4*)x;
    const int g8 = t >> 5;                    // stage/pool row phase (0..7, global)
    const int c4 = t & 31;                    // float4 column slot

    float m_run = -FLT_MAX, l_run = 0.0f;
    float4 pa = make_float4(0.f, 0.f, 0.f, 0.f);

    for (int cb = 0; cb < cnt; cb += 64) {
        const int rem = cnt - cb;             // >=1; rows >= rem are padding

        // ---- stage: global -> fp32 regs + bf16 swizzled LDS (converted ONCE) ----
        float4 xr[8];
        #pragma unroll
        for (int i = 0; i < 8; ++i) {
            int row = g8 + (i << 3);
            size_t gr = (size_t)min(start + cb + row, N - 1);   // clamp (pads masked)
            xr[i] = x4[gr * 32 + c4];
        }
        #pragma unroll
        for (int i = 0; i < 8; ++i) {
            int row = g8 + (i << 3);
            short4v b;
            b[0] = bf16b(xr[i].x); b[1] = bf16b(xr[i].y);
            b[2] = bf16b(xr[i].z); b[3] = bf16b(xr[i].w);
            *(short4v*)&XsB[(row << 7) | ((c4 << 2) ^ ((row & 7) << 3))] = b;
        }
        __syncthreads();                      // sync1: XsB ready (prev readers done)

        // ---- per row-tile: 8 MFMA + tanh/score epilogue (acc live = 8 VGPR) ----
        #pragma unroll
        for (int rt = 0; rt < 4; ++rt) {
            const int arow = (rt << 4) | al;
            const int rsw = (arow & 7) << 3;
            f32x4 a0 = (f32x4){0.f, 0.f, 0.f, 0.f};
            f32x4 a1 = (f32x4){0.f, 0.f, 0.f, 0.f};
            #pragma unroll
            for (int ks = 0; ks < 4; ++ks) {
                short8v af = *(const short8v*)&XsB[(arow << 7) | (((ks << 5) | (ah << 3)) ^ rsw)];
                a0 = __builtin_amdgcn_mfma_f32_16x16x32_bf16(af, wf[0][ks], a0, 0, 0, 0);
                a1 = __builtin_amdgcn_mfma_f32_16x16x32_bf16(af, wf[1][ks], a1, 0, 0, 0);
            }
            #pragma unroll
            for (int r = 0; r < 4; ++r) {     // C/D: channel=al, node row = rt*16+ah*4+r
                float s = swl[0] * tanh_fast(a0[r] + pbl[0])
                        + swl[1] * tanh_fast(a1[r] + pbl[1]);
                s += __shfl_xor(s, 1); s += __shfl_xor(s, 2);
                s += __shfl_xor(s, 4); s += __shfl_xor(s, 8);
                if (al == 0) ps[(((rt << 4) | (ah << 2) | r) << 2) | w] = s;
            }
        }
        __syncthreads();                      // sync2: ps complete, XsB reads done

        // ---- all-wave softmax: lane L owns row L (redundant across waves) ----
        float4 pp = *(const float4*)&ps[lane << 2];
        float sv = (lane < rem) ? (pp.x + pp.y + pp.z + pp.w + sb) : -FLT_MAX;
        float mx = sv;
        #pragma unroll
        for (int m = 1; m < 64; m <<= 1) mx = fmaxf(mx, __shfl_xor(mx, m));
        const float m_new = fmaxf(m_run, mx);
        float ev = (lane < rem) ? __expf(sv - m_new) : 0.f;
        float ssum = ev;
        #pragma unroll
        for (int m = 1; m < 64; m <<= 1) ssum += __shfl_xor(ssum, m);
        const float sc = __expf(m_run - m_new);       // first chunk: exp(-huge)=0
        m_run = m_new;
        l_run = l_run * sc + ssum;
        pa.x *= sc; pa.y *= sc; pa.z *= sc; pa.w *= sc;

        // ---- pooling accumulate (pure registers; e broadcast via shfl) ----
        #pragma unroll
        for (int i = 0; i < 8; ++i) {
            float em = __shfl(ev, g8 + (i << 3));     // 0 for pad rows
            pa.x += em * xr[i].x; pa.y += em * xr[i].y;
            pa.z += em * xr[i].z; pa.w += em * xr[i].w;
        }
    }

    // ---- cross-phase reduce (alias red onto XsB) + normalize + store ----
    float* red = (float*)XsB;                 // safe: all XsB reads ended at last sync2
    *(float4*)&red[(g8 << 7) + (c4 << 2)] = pa;
    __syncthreads();
    if (t < 32) {
        float4 v = make_float4(0.f, 0.f, 0.f, 0.f);
        #pragma unroll
        for (int j = 0; j < 8; ++j) {
            float4 r = *(const float4*)&red[(j << 7) + (t << 2)];
            v.x += r.x; v.y += r.y; v.z += r.z; v.w += r.w;
        }
        const float inv = 1.0f / fmaxf(l_run, 1e-30f);
        v.x *= inv; v.y *= inv; v.z *= inv; v.w *= inv;
        og4[t] = v;
    }
}

extern "C" void kernel_launch(void* const* d_in, const int* in_sizes, int n_in,
                              void* d_out, int out_size, void* d_ws, size_t ws_size,
                              hipStream_t stream) {
    const float* x       = (const float*)d_in[0];
    const float* proj_w  = (const float*)d_in[1];
    const float* proj_b  = (const float*)d_in[2];
    const float* score_w = (const float*)d_in[3];
    const float* score_b = (const float*)d_in[4];
    const int*   batch   = (const int*)d_in[5];

    const int N = in_sizes[0] / CDIM;
    const int G = out_size / CDIM;

    int*   seg   = (int*)d_ws;
    short* wfrag = (short*)((char*)d_ws + (((size_t)(G + 1) * 4 + 255) & ~(size_t)255));

    seg_bounds_kernel<<<(G + 255) / 256, 256, 0, stream>>>(batch, N, G, seg);
    wconv_kernel<<<8, 256, 0, stream>>>(proj_w, wfrag);
    pool_kernel<<<G, 256, 0, stream>>>(x, wfrag, proj_b, score_w, score_b,
                                       seg, (float*)d_out, N);
}